// Round 2
// baseline (320.933 us; speedup 1.0000x reference)
//
#include <hip/hip_runtime.h>
#include <hip/hip_bf16.h>
#include <stdint.h>
#include <stddef.h>

typedef unsigned short u16;
typedef __attribute__((ext_vector_type(8))) short bf16x8;
typedef __attribute__((ext_vector_type(4))) short bf16x4;
typedef __attribute__((ext_vector_type(4))) float f32x4;
typedef __attribute__((ext_vector_type(16))) float f32x16;
typedef __attribute__((ext_vector_type(4))) unsigned short u16x4;

#define MFMA_BF16 __builtin_amdgcn_mfma_f32_16x16x32_bf16
#define MFMA32    __builtin_amdgcn_mfma_f32_32x32x16_bf16

// exp2 on the hardware transcendental unit (v_exp_f32 IS 2^x)
#if defined(__has_builtin)
#if __has_builtin(__builtin_amdgcn_exp2f)
#define EXP2F(x) __builtin_amdgcn_exp2f(x)
#endif
#endif
#ifndef EXP2F
#define EXP2F(x) __expf((x) * 0.6931471805599453f)
#endif

// permlane32_swap: swaps hi-half of a with lo-half of b (both outputs used)
__device__ __forceinline__ void pl32swap(unsigned& a, unsigned& b) {
#if defined(__has_builtin) && __has_builtin(__builtin_amdgcn_permlane32_swap)
  typedef int v2i __attribute__((ext_vector_type(2)));
  v2i r = __builtin_amdgcn_permlane32_swap((int)a, (int)b, false, false);
  a = (unsigned)r.x;
  b = (unsigned)r.y;
#else
  asm volatile("v_permlane32_swap_b32 %0, %1" : "+v"(a), "+v"(b));
#endif
}

// raw barrier: wait own vmcnt (own async tile chunk landed) then barrier.
// Prefetch for the NEXT tile is issued AFTER this, so the wait only covers
// loads that flew during a full compute phase.
#define BAR_FULL asm volatile("s_waitcnt vmcnt(0)\n\ts_barrier" ::: "memory")

// Q pre-scale: HEAD_DIM^-0.5 * log2(e), so attention uses exp2 directly.
#define QSCALE 0.18033688011112042f

// round-to-nearest-even fp32 -> bf16
__device__ __forceinline__ u16 f2b(float x) {
  uint32_t u = __builtin_bit_cast(uint32_t, x);
  return (u16)((u + 0x7fffu + ((u >> 16) & 1u)) >> 16);
}

// packed fp32 pair -> bf16x2 in one u32 (v_cvt_pk_bf16_f32)
__device__ __forceinline__ unsigned pk2(float a, float b) {
  union { __hip_bfloat162 h; unsigned u; } c;
  c.h = __float22bfloat162_rn(make_float2(a, b));
  return c.u;
}

// async global->LDS, 16B per lane. LDS dst is wave-uniform base + lane*16.
__device__ __forceinline__ void async16(const void* g, void* l) {
  __builtin_amdgcn_global_load_lds((const __attribute__((address_space(1))) void*)g,
                                   (__attribute__((address_space(3))) void*)l, 16, 0, 0);
}

// ---------------------------------------------------------------- fused converts
__global__ void cvt_all(const float* __restrict__ x, const float* __restrict__ y,
                        const float* __restrict__ xqw, const float* __restrict__ yqw,
                        const float* __restrict__ xpw, const float* __restrict__ ypw,
                        u16* __restrict__ dst) {
  long i = ((long)blockIdx.x * 256 + threadIdx.x) * 4;
  const float* src;
  long off;
  if (i < 6291456)       { src = x;   off = 0; }
  else if (i < 12582912) { src = y;   off = 6291456; }
  else if (i < 14352384) { src = xqw; off = 12582912; }
  else if (i < 16121856) { src = yqw; off = 14352384; }
  else if (i < 16711680) { src = xpw; off = 16121856; }
  else                   { src = ypw; off = 16711680; }
  float4 v = *(const float4*)(src + (i - off));
  u16x4 o = { f2b(v.x), f2b(v.y), f2b(v.z), f2b(v.w) };
  *(u16x4*)(dst + i) = o;
}

// ---------------------------------------------------------------- QKV GEMM
__global__ __launch_bounds__(256, 2)
void qkv_gemm(const u16* __restrict__ Xb, const u16* __restrict__ Yb,
              const u16* __restrict__ Wx, const u16* __restrict__ Wy,
              u16* __restrict__ Qx, u16* __restrict__ Kx, u16* __restrict__ Vtx,
              u16* __restrict__ Qy, u16* __restrict__ Ky, u16* __restrict__ Vty) {
  __shared__ alignas(16) char smem[65536];  // As dbuf [0,32K), Bs dbuf [32K,64K); epilogue Ts[128][136]
  const int br = blockIdx.z;
  const u16* A = br ? Yb : Xb;
  const u16* W = br ? Wy : Wx;
  u16* Qd = br ? Qy : Qx;
  u16* Kd = br ? Ky : Kx;
  u16* Vd = br ? Vty : Vtx;
  const int m0 = blockIdx.x * 128;
  const int j0 = blockIdx.y * 128;
  const int tid = threadIdx.x;
  const int wave = tid >> 6, lane = tid & 63;
  const int quad = lane >> 4, l16 = lane & 15;
  const int wm = wave >> 1, wn = wave & 1;
  const int srow = wave * 32 + (lane >> 3);                 // +c*8
  const int scol = (((lane & 7) ^ ((lane >> 3) & 7)) * 8);  // swizzled chunk
  const int l7 = l16 & 7;

  auto stage = [&](int k0, int p) {
#pragma unroll
    for (int c = 0; c < 4; ++c) {
      async16(A + (size_t)(m0 + srow + c * 8) * 768 + k0 + scol,
              smem + p * 16384 + wave * 4096 + c * 1024);
      async16(W + (size_t)(j0 + srow + c * 8) * 768 + k0 + scol,
              smem + 32768 + p * 16384 + wave * 4096 + c * 1024);
    }
  };

  f32x4 acc[4][4] = {};
  stage(0, 0);

  for (int kt = 0; kt < 12; ++kt) {
    const int p = kt & 1;
    BAR_FULL;
    if (kt < 11) stage((kt + 1) * 64, p ^ 1);
    const u16* Ap = (const u16*)smem + p * 8192;
    const u16* Bp = (const u16*)smem + 16384 + p * 8192;
#pragma unroll
    for (int kc = 0; kc < 2; ++kc) {
      bf16x8 af[4], bfr[4];
#pragma unroll
      for (int t = 0; t < 4; ++t) {
        af[t]  = *(const bf16x8*)&Ap[(wm * 64 + t * 16 + l16) * 64 + (((kc * 4 + quad) ^ l7) * 8)];
        bfr[t] = *(const bf16x8*)&Bp[(wn * 64 + t * 16 + l16) * 64 + (((kc * 4 + quad) ^ l7) * 8)];
      }
#pragma unroll
      for (int mt = 0; mt < 4; ++mt)
#pragma unroll
        for (int nt = 0; nt < 4; ++nt)
          acc[mt][nt] = MFMA_BF16(af[mt], bfr[nt], acc[mt][nt], 0, 0, 0);
    }
  }

  __syncthreads();  // everyone done reading dbuf; safe to reuse as Ts
  u16* Ts = (u16*)smem;  // [128][136]
  const int s3 = j0 / 768;  // 0=Q 1=K 2=V, uniform per block

  if (s3 == 2) {
    // transpose to [j][m] so V^T rows (fixed d, contiguous n) read coalesced
#pragma unroll
    for (int mt = 0; mt < 4; ++mt)
#pragma unroll
      for (int nt = 0; nt < 4; ++nt) {
        const int j = wn * 64 + nt * 16 + l16;
        const int mb = wm * 64 + mt * 16 + quad * 4;
        u16x4 pk = { f2b(acc[mt][nt][0]), f2b(acc[mt][nt][1]),
                     f2b(acc[mt][nt][2]), f2b(acc[mt][nt][3]) };
        *(u16x4*)&Ts[j * 136 + mb] = pk;
      }
    __syncthreads();
#pragma unroll
    for (int rt = 0; rt < 8; ++rt) {
      const int j = wave * 32 + rt * 4 + (lane >> 4);
      const int mo = (lane & 15) * 8;
      bf16x8 v = *(const bf16x8*)&Ts[j * 136 + mo];
      const int jr = j0 + j - 1536;
      const int h = jr >> 6, d = jr & 63;
      const int gm = m0 + mo;
      const int b = gm >> 10, n = gm & 1023;
      *(bf16x8*)&Vd[((size_t)(b * 12 + h) * 64 + d) * 1024 + n] = v;
    }
  } else {
    const float qs = s3 ? 1.0f : QSCALE;
#pragma unroll
    for (int mt = 0; mt < 4; ++mt)
#pragma unroll
      for (int nt = 0; nt < 4; ++nt) {
        const int j = wn * 64 + nt * 16 + l16;
#pragma unroll
        for (int r = 0; r < 4; ++r) {
          const int m = wm * 64 + mt * 16 + quad * 4 + r;
          Ts[m * 136 + j] = f2b(acc[mt][nt][r] * qs);
        }
      }
    __syncthreads();
    u16* Dd = s3 ? Kd : Qd;
#pragma unroll
    for (int rt = 0; rt < 8; ++rt) {
      const int m = wave * 32 + rt * 4 + (lane >> 4);
      const int jh = (lane >> 3) & 1, jo = (lane & 7) * 8;
      bf16x8 v = *(const bf16x8*)&Ts[m * 136 + jh * 64 + jo];
      const int jr = j0 + jh * 64 + jo - s3 * 768;
      const int h = jr >> 6, d = jr & 63;  // d == jo
      const int gm = m0 + m;
      const int b = gm >> 10, n = gm & 1023;
      *(bf16x8*)&Dd[((size_t)(b * 12 + h) * 1024 + n) * 64 + d] = v;
    }
  }
}

// ---------------------------------------------------------------- flash attention
// 32x32 MFMA restructure: S^T via mfma_f32_32x32x16_bf16 (lane holds one q
// column: q=lane&31, kv=(r&3)+8*(r>>2)+4*hi). P=exp2(S^T) is re-aligned into
// the 32x32x16 A-operand with v_permlane32_swap_b32 pairs (VALU crossbar, no
// LDS traffic), so PV also runs full-rate 32x32x16 MFMAs instead of the
// previous half-rate 16x16x16. lsum moves off the matrix pipe: per-lane f32
// add-tree + one shfl_xor(32) fold at the end, shared via a tiny LDS table.
// Wave q-tile = 64 rows (2 x 32-col halves); K/V staging layout unchanged.
__global__ __launch_bounds__(256, 3)
void attn_kernel(const u16* __restrict__ Qx, const u16* __restrict__ Kx, const u16* __restrict__ Vtx,
                 const u16* __restrict__ Qy, const u16* __restrict__ Ky, const u16* __restrict__ Vty,
                 u16* __restrict__ Ox, u16* __restrict__ Oy) {
  __shared__ alignas(16) u16 Ks[2][64 * 64];   // [kv][d], 16B-chunk swizzled
  __shared__ alignas(16) u16 Vs[2][64 * 64];   // [d][kv], 16B-chunk swizzled
  const int br = blockIdx.z;
  const u16* Q = br ? Qy : Qx;
  const u16* K = br ? Ky : Kx;
  const u16* V = br ? Vtx : Vty;  // swapped-V cross attention
  u16* O = br ? Oy : Ox;
  const int bh = blockIdx.y;
  const int q0 = blockIdx.x * 256;
  const int tid = threadIdx.x;
  const int wave = tid >> 6, lane = tid & 63;
  const int l = lane & 31, hi = lane >> 5;
  const int l7 = lane & 7;
  const int r8 = (lane >> 3) & 7;
  const int sw = ((lane & 7) ^ r8) * 8;        // swizzled chunk (u16 offset)

  const u16* Qb = Q + (size_t)bh * 65536;
  const u16* Kb = K + (size_t)bh * 65536;
  const u16* Vb = V + (size_t)bh * 65536;

  const int krow = wave * 16 + r8;

  // prefetch tile 0 first so HBM latency overlaps the Q-fragment loads
#pragma unroll
  for (int c = 0; c < 2; ++c) {
    async16(Kb + (size_t)(krow + c * 8) * 64 + sw, (char*)Ks[0] + wave * 2048 + c * 1024);
    async16(Vb + (size_t)(krow + c * 8) * 1024 + sw, (char*)Vs[0] + wave * 2048 + c * 1024);
  }

  // loop-invariant Q fragments: wave owns 64 q rows (2 halves of 32 cols).
  // B-operand 32x32x16: col=lane&31 (q), k = hi*8+j (d within 16-chunk).
  bf16x8 qf[2][4];
#pragma unroll
  for (int qh = 0; qh < 2; ++qh)
#pragma unroll
    for (int dc = 0; dc < 4; ++dc)
      qf[qh][dc] = *(const bf16x8*)(Qb + (size_t)(q0 + wave * 64 + qh * 32 + l) * 64 + dc * 16 + hi * 8);

  f32x16 oacc[2][2] = {};   // [qh][dt]: row=q (crow), col=d=dt*32+l
  float lsum[2] = {0.f, 0.f};

  union FrU { unsigned u[4]; bf16x8 v; };

  for (int it = 0; it < 16; ++it) {
    const int p = it & 1;
    BAR_FULL;
    if (it < 15) {
      const int kv1 = (it + 1) * 64;
#pragma unroll
      for (int c = 0; c < 2; ++c) {
        async16(Kb + (size_t)(kv1 + krow + c * 8) * 64 + sw, (char*)Ks[p ^ 1] + wave * 2048 + c * 1024);
        async16(Vb + (size_t)(krow + c * 8) * 1024 + kv1 + sw, (char*)Vs[p ^ 1] + wave * 2048 + c * 1024);
      }
    }

    const u16* Kp = Ks[p];
    const u16* Vp = Vs[p];

#pragma unroll
    for (int s = 0; s < 2; ++s) {
      // K A-fragments: row = s*32+l (kv), k = dc*16 + hi*8 (d)
      bf16x8 kf[4];
#pragma unroll
      for (int dc = 0; dc < 4; ++dc)
        kf[dc] = *(const bf16x8*)&Kp[(s * 32 + l) * 64 + (((dc * 2 + hi) ^ l7) * 8)];

      FrU fragA[2][2];  // [qh][f]: PV A-operand, 16 kv each
#pragma unroll
      for (int qh = 0; qh < 2; ++qh) {
        // S^T = K Q^T : lane holds q=l, kv=(r&3)+8*(r>>2)+4*hi of this slab
        f32x16 st = {};
#pragma unroll
        for (int dc = 0; dc < 4; ++dc)
          st = MFMA32(kf[dc], qf[qh][dc], st, 0, 0, 0);
        float pv[16];
#pragma unroll
        for (int r = 0; r < 16; ++r) pv[r] = EXP2F(st[r]);
        // denominator: per-lane partial over this lane's kv subset (hi-fold at end)
        lsum[qh] += (((pv[0] + pv[1]) + (pv[2] + pv[3])) + ((pv[4] + pv[5]) + (pv[6] + pv[7])))
                  + (((pv[8] + pv[9]) + (pv[10] + pv[11])) + ((pv[12] + pv[13]) + (pv[14] + pv[15])));
        // pack to bf16 pairs: P[i] = kv {2i,2i+1} of crow order
        unsigned P[8];
#pragma unroll
        for (int i = 0; i < 8; ++i) P[i] = pk2(pv[2 * i], pv[2 * i + 1]);
        // permlane re-align: fragment f covers kv [f*16, f*16+16):
        //   pairs (P[4f],P[4f+2]) and (P[4f+1],P[4f+3]); both swap outputs used
#pragma unroll
        for (int f = 0; f < 2; ++f) {
          unsigned a0 = P[f * 4 + 0], b0 = P[f * 4 + 2];
          unsigned a1 = P[f * 4 + 1], b1 = P[f * 4 + 3];
          pl32swap(a0, b0);
          pl32swap(a1, b1);
          fragA[qh][f].u[0] = a0;  // k 0,1
          fragA[qh][f].u[1] = a1;  // k 2,3
          fragA[qh][f].u[2] = b0;  // k 4,5
          fragA[qh][f].u[3] = b1;  // k 6,7
        }
      }
      // PV: O += P @ V, full-rate 32x32x16. B-operand: col=l (d), k=hi*8+j (kv)
#pragma unroll
      for (int f = 0; f < 2; ++f)
#pragma unroll
        for (int dt = 0; dt < 2; ++dt) {
          bf16x8 vf = *(const bf16x8*)&Vp[(dt * 32 + l) * 64 + (((s * 4 + f * 2 + hi) ^ l7) * 8)];
          oacc[0][dt] = MFMA32(fragA[0][f].v, vf, oacc[0][dt], 0, 0, 0);
          oacc[1][dt] = MFMA32(fragA[1][f].v, vf, oacc[1][dt], 0, 0, 0);
        }
    }
  }

  // epilogue: fold hi-halves of lsum, invert, share per-wave via LDS (Ks[0] is
  // dead: last read of buffer 0 was it=14, fenced by it=15's barrier).
  float* LS = (float*)Ks[0] + wave * 64;
  {
    float t0 = lsum[0] + __shfl_xor(lsum[0], 32, 64);
    float t1 = lsum[1] + __shfl_xor(lsum[1], 32, 64);
    LS[l] = 1.0f / t0;        // hi=0/1 lanes write identical values
    LS[32 + l] = 1.0f / t1;
  }
  __syncthreads();

  const int b = bh / 12, h = bh % 12;
#pragma unroll
  for (int qh = 0; qh < 2; ++qh)
#pragma unroll
    for (int r = 0; r < 16; ++r) {
      const int cr = (r & 3) + 8 * (r >> 2) + 4 * hi;
      const float iv = LS[qh * 32 + cr];   // broadcast read (uniform per hi-half)
      const int qrow = q0 + wave * 64 + qh * 32 + cr;
      const size_t ob = ((size_t)(b * 1024 + qrow)) * 768 + h * 64;
#pragma unroll
      for (int dt = 0; dt < 2; ++dt)
        O[ob + dt * 32 + l] = f2b(oacc[qh][dt][r] * iv);
    }
}

// ---------------------------------------------------------------- proj GEMM + bias
__global__ __launch_bounds__(256, 2)
void proj_gemm(const u16* __restrict__ Ox, const u16* __restrict__ Oy,
               const u16* __restrict__ Pxw, const u16* __restrict__ Pyw,
               const float* __restrict__ bx, const float* __restrict__ by,
               float* __restrict__ out) {
  __shared__ alignas(16) char smem[65536];
  const int br = blockIdx.z;
  const u16* A = br ? Oy : Ox;
  const u16* W = br ? Pyw : Pxw;
  const float* bias = br ? by : bx;
  float* op = out + (size_t)br * 6291456;
  const int m0 = blockIdx.x * 128;
  const int j0 = blockIdx.y * 128;
  const int tid = threadIdx.x;
  const int wave = tid >> 6, lane = tid & 63;
  const int quad = lane >> 4, l16 = lane & 15;
  const int wm = wave >> 1, wn = wave & 1;
  const int srow = wave * 32 + (lane >> 3);
  const int scol = (((lane & 7) ^ ((lane >> 3) & 7)) * 8);
  const int l7 = l16 & 7;

  auto stage = [&](int k0, int p) {
#pragma unroll
    for (int c = 0; c < 4; ++c) {
      async16(A + (size_t)(m0 + srow + c * 8) * 768 + k0 + scol,
              smem + p * 16384 + wave * 4096 + c * 1024);
      async16(W + (size_t)(j0 + srow + c * 8) * 768 + k0 + scol,
              smem + 32768 + p * 16384 + wave * 4096 + c * 1024);
    }
  };

  f32x4 acc[4][4] = {};
  stage(0, 0);

  for (int kt = 0; kt < 12; ++kt) {
    const int p = kt & 1;
    BAR_FULL;
    if (kt < 11) stage((kt + 1) * 64, p ^ 1);
    const u16* Ap = (const u16*)smem + p * 8192;
    const u16* Bp = (const u16*)smem + 16384 + p * 8192;
#pragma unroll
    for (int kc = 0; kc < 2; ++kc) {
      bf16x8 af[4], bfr[4];
#pragma unroll
      for (int t = 0; t < 4; ++t) {
        af[t]  = *(const bf16x8*)&Ap[(wm * 64 + t * 16 + l16) * 64 + (((kc * 4 + quad) ^ l7) * 8)];
        bfr[t] = *(const bf16x8*)&Bp[(wn * 64 + t * 16 + l16) * 64 + (((kc * 4 + quad) ^ l7) * 8)];
      }
#pragma unroll
      for (int mt = 0; mt < 4; ++mt)
#pragma unroll
        for (int nt = 0; nt < 4; ++nt)
          acc[mt][nt] = MFMA_BF16(af[mt], bfr[nt], acc[mt][nt], 0, 0, 0);
    }
  }

#pragma unroll
  for (int mt = 0; mt < 4; ++mt) {
#pragma unroll
    for (int nt = 0; nt < 4; ++nt) {
      const int j = j0 + wn * 64 + nt * 16 + l16;
      const float bj = bias[j];
#pragma unroll
      for (int r = 0; r < 4; ++r) {
        const int m = m0 + wm * 64 + mt * 16 + quad * 4 + r;
        op[(size_t)m * 768 + j] = acc[mt][nt][r] + bj;
      }
    }
  }
}

// ---------------------------------------------------------------- launch
extern "C" void kernel_launch(void* const* d_in, const int* in_sizes, int n_in,
                              void* d_out, int out_size, void* d_ws, size_t ws_size,
                              hipStream_t stream) {
  (void)in_sizes; (void)n_in; (void)out_size; (void)ws_size;
  const float* x   = (const float*)d_in[0];
  const float* y   = (const float*)d_in[1];
  const float* xqw = (const float*)d_in[2];
  const float* yqw = (const float*)d_in[3];
  const float* xpw = (const float*)d_in[4];
  const float* xpb = (const float*)d_in[5];
  const float* ypw = (const float*)d_in[6];
  const float* ypb = (const float*)d_in[7];
  float* out = (float*)d_out;

  char* p = (char*)d_ws;
  u16* Xb  = (u16*)p; p += 12582912;   // contiguous bf16 block for cvt_all:
  u16* Yb  = (u16*)p; p += 12582912;   // Xb Yb Wxb Wyb Pxb Pyb
  u16* Wxb = (u16*)p; p += 3538944;
  u16* Wyb = (u16*)p; p += 3538944;
  u16* Pxb = (u16*)p; p += 1179648;
  u16* Pyb = (u16*)p; p += 1179648;
  u16* Qx  = (u16*)p; p += 12582912;   // [b,h,n,d] bf16 (pre-scaled by QSCALE)
  u16* Kx  = (u16*)p; p += 12582912;
  u16* Vtx = (u16*)p; p += 12582912;   // [b,h,d,n] bf16
  u16* Qy  = (u16*)p; p += 12582912;
  u16* Ky  = (u16*)p; p += 12582912;
  u16* Vty = (u16*)p; p += 12582912;
  u16* Ox  = Xb;  // alias: Xb/Yb dead after qkv_gemm (stream-ordered)
  u16* Oy  = Yb;

  cvt_all<<<16896, 256, 0, stream>>>(x, y, xqw, yqw, xpw, ypw, Xb);

  qkv_gemm<<<dim3(64, 18, 2), 256, 0, stream>>>(Xb, Yb, Wxb, Wyb,
                                                Qx, Kx, Vtx, Qy, Ky, Vty);
  attn_kernel<<<dim3(4, 96, 2), 256, 0, stream>>>(Qx, Kx, Vtx, Qy, Ky, Vty, Ox, Oy);
  proj_gemm<<<dim3(64, 6, 2), 256, 0, stream>>>(Ox, Oy, Pxb, Pyb, xpb, ypb, out);
}

// Round 3
// 277.089 us; speedup vs baseline: 1.1582x; 1.1582x over previous
//
#include <hip/hip_runtime.h>
#include <hip/hip_bf16.h>
#include <stdint.h>
#include <stddef.h>

typedef unsigned short u16;
typedef __attribute__((ext_vector_type(8))) short bf16x8;
typedef __attribute__((ext_vector_type(4))) short bf16x4;
typedef __attribute__((ext_vector_type(4))) float f32x4;
typedef __attribute__((ext_vector_type(16))) float f32x16;
typedef __attribute__((ext_vector_type(4))) unsigned short u16x4;

#define MFMA_BF16 __builtin_amdgcn_mfma_f32_16x16x32_bf16
#define MFMA32    __builtin_amdgcn_mfma_f32_32x32x16_bf16

// exp2 on the hardware transcendental unit (v_exp_f32 IS 2^x)
#if defined(__has_builtin)
#if __has_builtin(__builtin_amdgcn_exp2f)
#define EXP2F(x) __builtin_amdgcn_exp2f(x)
#endif
#endif
#ifndef EXP2F
#define EXP2F(x) __expf((x) * 0.6931471805599453f)
#endif

// permlane32_swap: swaps hi-half of a with lo-half of b (both outputs used)
__device__ __forceinline__ void pl32swap(unsigned& a, unsigned& b) {
#if defined(__has_builtin) && __has_builtin(__builtin_amdgcn_permlane32_swap)
  typedef int v2i __attribute__((ext_vector_type(2)));
  v2i r = __builtin_amdgcn_permlane32_swap((int)a, (int)b, false, false);
  a = (unsigned)r.x;
  b = (unsigned)r.y;
#else
  asm volatile("v_permlane32_swap_b32 %0, %1" : "+v"(a), "+v"(b));
#endif
}

// raw barrier: wait own vmcnt (own async tile chunk landed) then barrier.
// Prefetch for the NEXT tile is issued AFTER this, so the wait only covers
// loads that flew during a full compute phase.
#define BAR_FULL asm volatile("s_waitcnt vmcnt(0)\n\ts_barrier" ::: "memory")

// Q pre-scale: HEAD_DIM^-0.5 * log2(e), so attention uses exp2 directly.
#define QSCALE 0.18033688011112042f

// round-to-nearest-even fp32 -> bf16
__device__ __forceinline__ u16 f2b(float x) {
  uint32_t u = __builtin_bit_cast(uint32_t, x);
  return (u16)((u + 0x7fffu + ((u >> 16) & 1u)) >> 16);
}

// packed fp32 pair -> bf16x2 in one u32 (v_cvt_pk_bf16_f32)
__device__ __forceinline__ unsigned pk2(float a, float b) {
  union { __hip_bfloat162 h; unsigned u; } c;
  c.h = __float22bfloat162_rn(make_float2(a, b));
  return c.u;
}

// async global->LDS, 16B per lane. LDS dst is wave-uniform base + lane*16.
__device__ __forceinline__ void async16(const void* g, void* l) {
  __builtin_amdgcn_global_load_lds((const __attribute__((address_space(1))) void*)g,
                                   (__attribute__((address_space(3))) void*)l, 16, 0, 0);
}

// ---------------------------------------------------------------- fused converts
__global__ void cvt_all(const float* __restrict__ x, const float* __restrict__ y,
                        const float* __restrict__ xqw, const float* __restrict__ yqw,
                        const float* __restrict__ xpw, const float* __restrict__ ypw,
                        u16* __restrict__ dst) {
  long i = ((long)blockIdx.x * 256 + threadIdx.x) * 4;
  const float* src;
  long off;
  if (i < 6291456)       { src = x;   off = 0; }
  else if (i < 12582912) { src = y;   off = 6291456; }
  else if (i < 14352384) { src = xqw; off = 12582912; }
  else if (i < 16121856) { src = yqw; off = 14352384; }
  else if (i < 16711680) { src = xpw; off = 16121856; }
  else                   { src = ypw; off = 16711680; }
  float4 v = *(const float4*)(src + (i - off));
  u16x4 o = { f2b(v.x), f2b(v.y), f2b(v.z), f2b(v.w) };
  *(u16x4*)(dst + i) = o;
}

// ---------------------------------------------------------------- QKV GEMM
__global__ __launch_bounds__(256, 2)
void qkv_gemm(const u16* __restrict__ Xb, const u16* __restrict__ Yb,
              const u16* __restrict__ Wx, const u16* __restrict__ Wy,
              u16* __restrict__ Qx, u16* __restrict__ Kx, u16* __restrict__ Vtx,
              u16* __restrict__ Qy, u16* __restrict__ Ky, u16* __restrict__ Vty) {
  __shared__ alignas(16) char smem[65536];  // As dbuf [0,32K), Bs dbuf [32K,64K); epilogue Ts[128][136]
  const int br = blockIdx.z;
  const u16* A = br ? Yb : Xb;
  const u16* W = br ? Wy : Wx;
  u16* Qd = br ? Qy : Qx;
  u16* Kd = br ? Ky : Kx;
  u16* Vd = br ? Vty : Vtx;
  const int m0 = blockIdx.x * 128;
  const int j0 = blockIdx.y * 128;
  const int tid = threadIdx.x;
  const int wave = tid >> 6, lane = tid & 63;
  const int quad = lane >> 4, l16 = lane & 15;
  const int wm = wave >> 1, wn = wave & 1;
  const int srow = wave * 32 + (lane >> 3);                 // +c*8
  const int scol = (((lane & 7) ^ ((lane >> 3) & 7)) * 8);  // swizzled chunk
  const int l7 = l16 & 7;

  auto stage = [&](int k0, int p) {
#pragma unroll
    for (int c = 0; c < 4; ++c) {
      async16(A + (size_t)(m0 + srow + c * 8) * 768 + k0 + scol,
              smem + p * 16384 + wave * 4096 + c * 1024);
      async16(W + (size_t)(j0 + srow + c * 8) * 768 + k0 + scol,
              smem + 32768 + p * 16384 + wave * 4096 + c * 1024);
    }
  };

  f32x4 acc[4][4] = {};
  stage(0, 0);

  for (int kt = 0; kt < 12; ++kt) {
    const int p = kt & 1;
    BAR_FULL;
    if (kt < 11) stage((kt + 1) * 64, p ^ 1);
    const u16* Ap = (const u16*)smem + p * 8192;
    const u16* Bp = (const u16*)smem + 16384 + p * 8192;
#pragma unroll
    for (int kc = 0; kc < 2; ++kc) {
      bf16x8 af[4], bfr[4];
#pragma unroll
      for (int t = 0; t < 4; ++t) {
        af[t]  = *(const bf16x8*)&Ap[(wm * 64 + t * 16 + l16) * 64 + (((kc * 4 + quad) ^ l7) * 8)];
        bfr[t] = *(const bf16x8*)&Bp[(wn * 64 + t * 16 + l16) * 64 + (((kc * 4 + quad) ^ l7) * 8)];
      }
#pragma unroll
      for (int mt = 0; mt < 4; ++mt)
#pragma unroll
        for (int nt = 0; nt < 4; ++nt)
          acc[mt][nt] = MFMA_BF16(af[mt], bfr[nt], acc[mt][nt], 0, 0, 0);
    }
  }

  __syncthreads();  // everyone done reading dbuf; safe to reuse as Ts
  u16* Ts = (u16*)smem;  // [128][136]
  const int s3 = j0 / 768;  // 0=Q 1=K 2=V, uniform per block

  if (s3 == 2) {
    // transpose to [j][m] so V^T rows (fixed d, contiguous n) read coalesced
#pragma unroll
    for (int mt = 0; mt < 4; ++mt)
#pragma unroll
      for (int nt = 0; nt < 4; ++nt) {
        const int j = wn * 64 + nt * 16 + l16;
        const int mb = wm * 64 + mt * 16 + quad * 4;
        u16x4 pk = { f2b(acc[mt][nt][0]), f2b(acc[mt][nt][1]),
                     f2b(acc[mt][nt][2]), f2b(acc[mt][nt][3]) };
        *(u16x4*)&Ts[j * 136 + mb] = pk;
      }
    __syncthreads();
#pragma unroll
    for (int rt = 0; rt < 8; ++rt) {
      const int j = wave * 32 + rt * 4 + (lane >> 4);
      const int mo = (lane & 15) * 8;
      bf16x8 v = *(const bf16x8*)&Ts[j * 136 + mo];
      const int jr = j0 + j - 1536;
      const int h = jr >> 6, d = jr & 63;
      const int gm = m0 + mo;
      const int b = gm >> 10, n = gm & 1023;
      *(bf16x8*)&Vd[((size_t)(b * 12 + h) * 64 + d) * 1024 + n] = v;
    }
  } else {
    const float qs = s3 ? 1.0f : QSCALE;
#pragma unroll
    for (int mt = 0; mt < 4; ++mt)
#pragma unroll
      for (int nt = 0; nt < 4; ++nt) {
        const int j = wn * 64 + nt * 16 + l16;
#pragma unroll
        for (int r = 0; r < 4; ++r) {
          const int m = wm * 64 + mt * 16 + quad * 4 + r;
          Ts[m * 136 + j] = f2b(acc[mt][nt][r] * qs);
        }
      }
    __syncthreads();
    u16* Dd = s3 ? Kd : Qd;
#pragma unroll
    for (int rt = 0; rt < 8; ++rt) {
      const int m = wave * 32 + rt * 4 + (lane >> 4);
      const int jh = (lane >> 3) & 1, jo = (lane & 7) * 8;
      bf16x8 v = *(const bf16x8*)&Ts[m * 136 + jh * 64 + jo];
      const int jr = j0 + jh * 64 + jo - s3 * 768;
      const int h = jr >> 6, d = jr & 63;  // d == jo
      const int gm = m0 + m;
      const int b = gm >> 10, n = gm & 1023;
      *(bf16x8*)&Dd[((size_t)(b * 12 + h) * 1024 + n) * 64 + d] = v;
    }
  }
}

// ---------------------------------------------------------------- flash attention
// 32x32 MFMA structure: S^T via mfma_f32_32x32x16_bf16 (lane holds one q
// column: q=lane&31, kv=(r&3)+8*(r>>2)+4*hi). P=exp2(S^T) is re-aligned into
// the 32x32x16 A-operand with v_permlane32_swap_b32 pairs (VALU crossbar, no
// LDS traffic), so PV also runs full-rate 32x32x16 MFMAs. lsum off the matrix
// pipe: per-lane f32 add-tree + one shfl_xor(32) fold at the end.
// launch_bounds MUST stay (256,2): at 3 waves/SIMD the unified VGPR budget
// (512/3) forces accumulator spill -> +240MB scratch traffic (measured R2).
__global__ __launch_bounds__(256, 2)
void attn_kernel(const u16* __restrict__ Qx, const u16* __restrict__ Kx, const u16* __restrict__ Vtx,
                 const u16* __restrict__ Qy, const u16* __restrict__ Ky, const u16* __restrict__ Vty,
                 u16* __restrict__ Ox, u16* __restrict__ Oy) {
  __shared__ alignas(16) u16 Ks[2][64 * 64];   // [kv][d], 16B-chunk swizzled
  __shared__ alignas(16) u16 Vs[2][64 * 64];   // [d][kv], 16B-chunk swizzled
  const int br = blockIdx.z;
  const u16* Q = br ? Qy : Qx;
  const u16* K = br ? Ky : Kx;
  const u16* V = br ? Vtx : Vty;  // swapped-V cross attention
  u16* O = br ? Oy : Ox;
  const int bh = blockIdx.y;
  const int q0 = blockIdx.x * 256;
  const int tid = threadIdx.x;
  const int wave = tid >> 6, lane = tid & 63;
  const int l = lane & 31, hi = lane >> 5;
  const int l7 = lane & 7;
  const int r8 = (lane >> 3) & 7;
  const int sw = ((lane & 7) ^ r8) * 8;        // swizzled chunk (u16 offset)

  const u16* Qb = Q + (size_t)bh * 65536;
  const u16* Kb = K + (size_t)bh * 65536;
  const u16* Vb = V + (size_t)bh * 65536;

  const int krow = wave * 16 + r8;

  // prefetch tile 0 first so HBM latency overlaps the Q-fragment loads
#pragma unroll
  for (int c = 0; c < 2; ++c) {
    async16(Kb + (size_t)(krow + c * 8) * 64 + sw, (char*)Ks[0] + wave * 2048 + c * 1024);
    async16(Vb + (size_t)(krow + c * 8) * 1024 + sw, (char*)Vs[0] + wave * 2048 + c * 1024);
  }

  // loop-invariant Q fragments: wave owns 64 q rows (2 halves of 32 cols).
  // B-operand 32x32x16: col=lane&31 (q), k = hi*8+j (d within 16-chunk).
  bf16x8 qf[2][4];
#pragma unroll
  for (int qh = 0; qh < 2; ++qh)
#pragma unroll
    for (int dc = 0; dc < 4; ++dc)
      qf[qh][dc] = *(const bf16x8*)(Qb + (size_t)(q0 + wave * 64 + qh * 32 + l) * 64 + dc * 16 + hi * 8);

  f32x16 oacc[2][2] = {};   // [qh][dt]: row=q (crow), col=d=dt*32+l
  float lsum[2] = {0.f, 0.f};

  union FrU { unsigned u[4]; bf16x8 v; };

  for (int it = 0; it < 16; ++it) {
    const int p = it & 1;
    BAR_FULL;
    if (it < 15) {
      const int kv1 = (it + 1) * 64;
#pragma unroll
      for (int c = 0; c < 2; ++c) {
        async16(Kb + (size_t)(kv1 + krow + c * 8) * 64 + sw, (char*)Ks[p ^ 1] + wave * 2048 + c * 1024);
        async16(Vb + (size_t)(krow + c * 8) * 1024 + kv1 + sw, (char*)Vs[p ^ 1] + wave * 2048 + c * 1024);
      }
    }

    const u16* Kp = Ks[p];
    const u16* Vp = Vs[p];

#pragma unroll
    for (int s = 0; s < 2; ++s) {
      // K A-fragments: row = s*32+l (kv), k = dc*16 + hi*8 (d)
      bf16x8 kf[4];
#pragma unroll
      for (int dc = 0; dc < 4; ++dc)
        kf[dc] = *(const bf16x8*)&Kp[(s * 32 + l) * 64 + (((dc * 2 + hi) ^ l7) * 8)];

      FrU fragA[2][2];  // [qh][f]: PV A-operand, 16 kv each
#pragma unroll
      for (int qh = 0; qh < 2; ++qh) {
        // S^T = K Q^T : lane holds q=l, kv=(r&3)+8*(r>>2)+4*hi of this slab
        f32x16 st = {};
#pragma unroll
        for (int dc = 0; dc < 4; ++dc)
          st = MFMA32(kf[dc], qf[qh][dc], st, 0, 0, 0);
        float pv[16];
#pragma unroll
        for (int r = 0; r < 16; ++r) pv[r] = EXP2F(st[r]);
        // denominator: per-lane partial over this lane's kv subset (hi-fold at end)
        lsum[qh] += (((pv[0] + pv[1]) + (pv[2] + pv[3])) + ((pv[4] + pv[5]) + (pv[6] + pv[7])))
                  + (((pv[8] + pv[9]) + (pv[10] + pv[11])) + ((pv[12] + pv[13]) + (pv[14] + pv[15])));
        // pack to bf16 pairs: P[i] = kv {2i,2i+1} of crow order
        unsigned P[8];
#pragma unroll
        for (int i = 0; i < 8; ++i) P[i] = pk2(pv[2 * i], pv[2 * i + 1]);
        // permlane re-align: fragment f covers kv [f*16, f*16+16):
        //   pairs (P[4f],P[4f+2]) and (P[4f+1],P[4f+3]); both swap outputs used
#pragma unroll
        for (int f = 0; f < 2; ++f) {
          unsigned a0 = P[f * 4 + 0], b0 = P[f * 4 + 2];
          unsigned a1 = P[f * 4 + 1], b1 = P[f * 4 + 3];
          pl32swap(a0, b0);
          pl32swap(a1, b1);
          fragA[qh][f].u[0] = a0;  // k 0,1
          fragA[qh][f].u[1] = a1;  // k 2,3
          fragA[qh][f].u[2] = b0;  // k 4,5
          fragA[qh][f].u[3] = b1;  // k 6,7
        }
      }
      // PV: O += P @ V, full-rate 32x32x16. B-operand: col=l (d), k=hi*8+j (kv)
#pragma unroll
      for (int f = 0; f < 2; ++f)
#pragma unroll
        for (int dt = 0; dt < 2; ++dt) {
          bf16x8 vf = *(const bf16x8*)&Vp[(dt * 32 + l) * 64 + (((s * 4 + f * 2 + hi) ^ l7) * 8)];
          oacc[0][dt] = MFMA32(fragA[0][f].v, vf, oacc[0][dt], 0, 0, 0);
          oacc[1][dt] = MFMA32(fragA[1][f].v, vf, oacc[1][dt], 0, 0, 0);
        }
    }
  }

  // epilogue: fold hi-halves of lsum, invert, share per-wave via LDS (Ks[0] is
  // dead: last read of buffer 0 was it=14, fenced by it=15's barrier).
  float* LS = (float*)Ks[0] + wave * 64;
  {
    float t0 = lsum[0] + __shfl_xor(lsum[0], 32, 64);
    float t1 = lsum[1] + __shfl_xor(lsum[1], 32, 64);
    LS[l] = 1.0f / t0;        // hi=0/1 lanes write identical values
    LS[32 + l] = 1.0f / t1;
  }
  __syncthreads();

  const int b = bh / 12, h = bh % 12;
#pragma unroll
  for (int qh = 0; qh < 2; ++qh)
#pragma unroll
    for (int r = 0; r < 16; ++r) {
      const int cr = (r & 3) + 8 * (r >> 2) + 4 * hi;
      const float iv = LS[qh * 32 + cr];   // broadcast read (uniform per hi-half)
      const int qrow = q0 + wave * 64 + qh * 32 + cr;
      const size_t ob = ((size_t)(b * 1024 + qrow)) * 768 + h * 64;
#pragma unroll
      for (int dt = 0; dt < 2; ++dt)
        O[ob + dt * 32 + l] = f2b(oacc[qh][dt][r] * iv);
    }
}

// ---------------------------------------------------------------- proj GEMM + bias
__global__ __launch_bounds__(256, 2)
void proj_gemm(const u16* __restrict__ Ox, const u16* __restrict__ Oy,
               const u16* __restrict__ Pxw, const u16* __restrict__ Pyw,
               const float* __restrict__ bx, const float* __restrict__ by,
               float* __restrict__ out) {
  __shared__ alignas(16) char smem[65536];
  const int br = blockIdx.z;
  const u16* A = br ? Oy : Ox;
  const u16* W = br ? Pyw : Pxw;
  const float* bias = br ? by : bx;
  float* op = out + (size_t)br * 6291456;
  const int m0 = blockIdx.x * 128;
  const int j0 = blockIdx.y * 128;
  const int tid = threadIdx.x;
  const int wave = tid >> 6, lane = tid & 63;
  const int quad = lane >> 4, l16 = lane & 15;
  const int wm = wave >> 1, wn = wave & 1;
  const int srow = wave * 32 + (lane >> 3);
  const int scol = (((lane & 7) ^ ((lane >> 3) & 7)) * 8);
  const int l7 = l16 & 7;

  auto stage = [&](int k0, int p) {
#pragma unroll
    for (int c = 0; c < 4; ++c) {
      async16(A + (size_t)(m0 + srow + c * 8) * 768 + k0 + scol,
              smem + p * 16384 + wave * 4096 + c * 1024);
      async16(W + (size_t)(j0 + srow + c * 8) * 768 + k0 + scol,
              smem + 32768 + p * 16384 + wave * 4096 + c * 1024);
    }
  };

  f32x4 acc[4][4] = {};
  stage(0, 0);

  for (int kt = 0; kt < 12; ++kt) {
    const int p = kt & 1;
    BAR_FULL;
    if (kt < 11) stage((kt + 1) * 64, p ^ 1);
    const u16* Ap = (const u16*)smem + p * 8192;
    const u16* Bp = (const u16*)smem + 16384 + p * 8192;
#pragma unroll
    for (int kc = 0; kc < 2; ++kc) {
      bf16x8 af[4], bfr[4];
#pragma unroll
      for (int t = 0; t < 4; ++t) {
        af[t]  = *(const bf16x8*)&Ap[(wm * 64 + t * 16 + l16) * 64 + (((kc * 4 + quad) ^ l7) * 8)];
        bfr[t] = *(const bf16x8*)&Bp[(wn * 64 + t * 16 + l16) * 64 + (((kc * 4 + quad) ^ l7) * 8)];
      }
#pragma unroll
      for (int mt = 0; mt < 4; ++mt)
#pragma unroll
        for (int nt = 0; nt < 4; ++nt)
          acc[mt][nt] = MFMA_BF16(af[mt], bfr[nt], acc[mt][nt], 0, 0, 0);
    }
  }

#pragma unroll
  for (int mt = 0; mt < 4; ++mt) {
#pragma unroll
    for (int nt = 0; nt < 4; ++nt) {
      const int j = j0 + wn * 64 + nt * 16 + l16;
      const float bj = bias[j];
#pragma unroll
      for (int r = 0; r < 4; ++r) {
        const int m = m0 + wm * 64 + mt * 16 + quad * 4 + r;
        op[(size_t)m * 768 + j] = acc[mt][nt][r] + bj;
      }
    }
  }
}

// ---------------------------------------------------------------- launch
extern "C" void kernel_launch(void* const* d_in, const int* in_sizes, int n_in,
                              void* d_out, int out_size, void* d_ws, size_t ws_size,
                              hipStream_t stream) {
  (void)in_sizes; (void)n_in; (void)out_size; (void)ws_size;
  const float* x   = (const float*)d_in[0];
  const float* y   = (const float*)d_in[1];
  const float* xqw = (const float*)d_in[2];
  const float* yqw = (const float*)d_in[3];
  const float* xpw = (const float*)d_in[4];
  const float* xpb = (const float*)d_in[5];
  const float* ypw = (const float*)d_in[6];
  const float* ypb = (const float*)d_in[7];
  float* out = (float*)d_out;

  char* p = (char*)d_ws;
  u16* Xb  = (u16*)p; p += 12582912;   // contiguous bf16 block for cvt_all:
  u16* Yb  = (u16*)p; p += 12582912;   // Xb Yb Wxb Wyb Pxb Pyb
  u16* Wxb = (u16*)p; p += 3538944;
  u16* Wyb = (u16*)p; p += 3538944;
  u16* Pxb = (u16*)p; p += 1179648;
  u16* Pyb = (u16*)p; p += 1179648;
  u16* Qx  = (u16*)p; p += 12582912;   // [b,h,n,d] bf16 (pre-scaled by QSCALE)
  u16* Kx  = (u16*)p; p += 12582912;
  u16* Vtx = (u16*)p; p += 12582912;   // [b,h,d,n] bf16
  u16* Qy  = (u16*)p; p += 12582912;
  u16* Ky  = (u16*)p; p += 12582912;
  u16* Vty = (u16*)p; p += 12582912;
  u16* Ox  = Xb;  // alias: Xb/Yb dead after qkv_gemm (stream-ordered)
  u16* Oy  = Yb;

  cvt_all<<<16896, 256, 0, stream>>>(x, y, xqw, yqw, xpw, ypw, Xb);

  qkv_gemm<<<dim3(64, 18, 2), 256, 0, stream>>>(Xb, Yb, Wxb, Wyb,
                                                Qx, Kx, Vtx, Qy, Ky, Vty);
  attn_kernel<<<dim3(4, 96, 2), 256, 0, stream>>>(Qx, Kx, Vtx, Qy, Ky, Vty, Ox, Oy);
  proj_gemm<<<dim3(64, 6, 2), 256, 0, stream>>>(Ox, Oy, Pxb, Pyb, xpb, ypb, out);
}